// Round 6
// baseline (32.877 us; speedup 1.0000x reference)
//
#include <hip/hip_runtime.h>
#include <hip/hip_bf16.h>
#include <math.h>

#define QN 8192
#define CN 64
#define SHOT 5
#define DN 512

#define THREADS 512
#define NW 8                 // waves per block
#define BQ 32                // queries per block -> grid 256 = 1 block/CU
#define CHUNK_D 128          // d's per staged chunk
#define NCHUNK (DN / CHUNK_D)

// --- proto kernel: proto[c][d] = mean over SHOT of y[c][s][d] (plain layout) ---
__global__ void proto_kernel(const float* __restrict__ y, float* __restrict__ proto) {
    int idx = blockIdx.x * blockDim.x + threadIdx.x;
    if (idx < CN * DN) {
        int c = idx >> 9;
        int d = idx & (DN - 1);
        float s = 0.f;
#pragma unroll
        for (int sh = 0; sh < SHOT; ++sh)
            s += y[(c * SHOT + sh) * DN + d];
        proto[idx] = s * (1.0f / SHOT);
    }
}

// --- fused dist + softmax: 32q x 64c per block, 4q x 8c register tile/thread ---
__global__ __launch_bounds__(THREADS, 2) void dist_kernel(
        const float* __restrict__ x,
        const float* __restrict__ proto,
        float* __restrict__ out) {
    __shared__ __align__(16) float lds[24576];     // 96 KiB
    float4* xb = (float4*)lds;                     // [2][32 rows][32 f4] = 32 KiB
    float4* pb = (float4*)lds + 2048;              // [2][64 rows][32 f4] = 64 KiB

    const int tid  = threadIdx.x;
    const int lane = tid & 63;
    const int wave = __builtin_amdgcn_readfirstlane(tid >> 6);
    const int q0   = blockIdx.x * BQ;
    const int qg   = lane >> 3;                    // 0..7 (q-group of 4)
    const int cg   = lane & 7;                     // 0..7 (c-group of 8)
    const int lhi  = lane >> 5;
    const int llo  = lane & 31;

    // DMA one 48 KB chunk: 2 x-instrs + 4 p-instrs per wave = vmcnt 6/chunk.
    // LDS dest linear; bank-swizzle (col ^ row-group) applied on the GLOBAL src.
    auto issue = [&](int k) {
        const int xbase = (k & 1) * 1024;
        const int pbase = (k & 1) * 2048;
#pragma unroll
        for (int tt = 0; tt < 2; ++tt) {
            int t = wave * 2 + tt;                 // 0..15, 2 q-rows each
            int q = 2 * t + lhi;
            int col = llo ^ ((q >> 2) & 7);
            const float* src = x + (size_t)(q0 + q) * DN + k * CHUNK_D + col * 4;
            __builtin_amdgcn_global_load_lds(
                (const __attribute__((address_space(1))) void*)src,
                (__attribute__((address_space(3))) void*)(xb + xbase + t * 64), 16, 0, 0);
        }
#pragma unroll
        for (int tt = 0; tt < 4; ++tt) {
            int t = wave * 4 + tt;                 // 0..31, 2 c-rows each
            int c = 2 * t + lhi;
            int col = llo ^ ((c >> 3) & 7);
            const float* src = proto + (size_t)c * DN + k * CHUNK_D + col * 4;
            __builtin_amdgcn_global_load_lds(
                (const __attribute__((address_space(1))) void*)src,
                (__attribute__((address_space(3))) void*)(pb + pbase + t * 64), 16, 0, 0);
        }
    };

    float acc[4][8];
#pragma unroll
    for (int i = 0; i < 4; ++i)
#pragma unroll
        for (int j = 0; j < 8; ++j) acc[i][j] = 0.f;

    issue(0);
    for (int k = 0; k < NCHUNK; ++k) {
        if (k + 1 < NCHUNK) {
            issue(k + 1);                              // next chunk stays in flight
            asm volatile("s_waitcnt vmcnt(6)" ::: "memory");   // chunk k landed
        } else {
            asm volatile("s_waitcnt vmcnt(0)" ::: "memory");
        }
        __builtin_amdgcn_s_barrier();
        __builtin_amdgcn_sched_barrier(0);

        const float4* xc = xb + (k & 1) * 1024;
        const float4* pc = pb + (k & 1) * 2048;
#pragma unroll
        for (int ft = 0; ft < 4; ++ft) {
            const int f = wave * 4 + ft;               // wave's 16-d sub-slice
            float4 xf[4];
#pragma unroll
            for (int i = 0; i < 4; ++i)
                xf[i] = xc[(qg * 4 + i) * 32 + (f ^ qg)];   // 8 distinct quads, no conflict
#pragma unroll
            for (int j = 0; j < 8; ++j) {
                float4 pf = pc[(cg * 8 + j) * 32 + (f ^ cg)];
#pragma unroll
                for (int i = 0; i < 4; ++i)
                    acc[i][j] += fabsf(xf[i].x - pf.x) + fabsf(xf[i].y - pf.y)
                               + fabsf(xf[i].z - pf.z) + fabsf(xf[i].w - pf.w);
            }
        }
        __builtin_amdgcn_sched_barrier(0);
        __builtin_amdgcn_s_barrier();                  // all waves done with this buf
    }

    // --- reduce the 8 wave-partials in LDS, then fused softmax ---
    float* red = lds;                                  // [8][32][65] = 66,560 B
#pragma unroll
    for (int i = 0; i < 4; ++i)
#pragma unroll
        for (int j = 0; j < 8; ++j)
            red[(wave * 32 + qg * 4 + i) * 65 + cg * 8 + j] = acc[i][j];
    __syncthreads();                                   // vmcnt already drained

    // wave w owns q rows [w*4, w*4+4); lane = class
#pragma unroll
    for (int r = 0; r < 4; ++r) {
        int q = wave * 4 + r;
        float s = 0.f;
#pragma unroll
        for (int ww = 0; ww < 8; ++ww)
            s += red[(ww * 32 + q) * 65 + lane];
        float nd = -s;
        float m = nd;
#pragma unroll
        for (int off = 32; off; off >>= 1)
            m = fmaxf(m, __shfl_xor(m, off, 64));
        float e = __expf(nd - m);
        float t = e;
#pragma unroll
        for (int off = 32; off; off >>= 1)
            t += __shfl_xor(t, off, 64);
        out[(size_t)(q0 + q) * CN + lane] = e / t;
    }
}

extern "C" void kernel_launch(void* const* d_in, const int* in_sizes, int n_in,
                              void* d_out, int out_size, void* d_ws, size_t ws_size,
                              hipStream_t stream) {
    const float* x = (const float*)d_in[0];   // [8192, 512]
    const float* y = (const float*)d_in[1];   // [64, 5, 512]
    float* out     = (float*)d_out;           // [8192, 64]
    float* proto   = (float*)d_ws;            // [64, 512] scratch

    proto_kernel<<<(CN * DN + 255) / 256, 256, 0, stream>>>(y, proto);
    dist_kernel<<<QN / BQ, THREADS, 0, stream>>>(x, proto, out);
}

// Round 7
// 32.875 us; speedup vs baseline: 1.0001x; 1.0001x over previous
//
#include <hip/hip_runtime.h>
#include <hip/hip_bf16.h>
#include <math.h>

#define QN 8192
#define CN 64
#define SHOT 5
#define DN 512

#define THREADS 512
#define BQ 32                // queries per block -> grid 256 = 1 block/CU
#define CHUNK_D 128          // d's per staged chunk
#define NCHUNK (DN / CHUNK_D)

// --- proto kernel: proto[c][d] = mean over SHOT of y[c][s][d] ---
__global__ void proto_kernel(const float* __restrict__ y, float* __restrict__ proto) {
    int idx = blockIdx.x * blockDim.x + threadIdx.x;
    if (idx < CN * DN) {
        int c = idx >> 9;
        int d = idx & (DN - 1);
        float s = 0.f;
#pragma unroll
        for (int sh = 0; sh < SHOT; ++sh)
            s += y[(c * SHOT + sh) * DN + d];
        proto[idx] = s * (1.0f / SHOT);
    }
}

// --- fused dist + softmax: 32q x 64c per block, 4q x 8c register tile/thread ---
// Identical to round 6 EXCEPT the chunk loop is forced rolled (I$ fix).
__global__ __launch_bounds__(THREADS, 2) void dist_kernel(
        const float* __restrict__ x,
        const float* __restrict__ proto,
        float* __restrict__ out) {
    __shared__ __align__(16) float lds[24576];     // 96 KiB
    float4* xb = (float4*)lds;                     // [2][1024] f4 = 32 KiB
    float4* pb = (float4*)lds + 2048;              // [2][2048] f4 = 64 KiB

    const int tid  = threadIdx.x;
    const int lane = tid & 63;
    const int wave = __builtin_amdgcn_readfirstlane(tid >> 6);
    const int q0   = blockIdx.x * BQ;
    const int qg   = lane >> 3;                    // 0..7 (q-group of 4)
    const int cg   = lane & 7;                     // 0..7 (c-group of 8)
    const int lhi  = lane >> 5;
    const int llo  = lane & 31;

    // DMA one 48 KB chunk: 2 x-instrs + 4 p-instrs per wave = vmcnt 6/chunk.
    // LDS dest linear; bank-swizzle (col ^ row-group) applied on the GLOBAL src.
    auto issue = [&](int k) {
        const int xo = (k & 1) << 10;
        const int po = (k & 1) << 11;
#pragma unroll
        for (int tt = 0; tt < 2; ++tt) {
            int t = wave * 2 + tt;                 // 2 q-rows per instr
            int q = 2 * t + lhi;
            int col = llo ^ ((q >> 2) & 7);
            const float* src = x + (size_t)(q0 + q) * DN + k * CHUNK_D + col * 4;
            __builtin_amdgcn_global_load_lds(
                (const __attribute__((address_space(1))) void*)src,
                (__attribute__((address_space(3))) void*)(xb + xo + t * 64), 16, 0, 0);
        }
#pragma unroll
        for (int tt = 0; tt < 4; ++tt) {
            int t = wave * 4 + tt;                 // 2 c-rows per instr
            int c = 2 * t + lhi;
            int col = llo ^ ((c >> 3) & 7);
            const float* src = proto + (size_t)c * DN + k * CHUNK_D + col * 4;
            __builtin_amdgcn_global_load_lds(
                (const __attribute__((address_space(1))) void*)src,
                (__attribute__((address_space(3))) void*)(pb + po + t * 64), 16, 0, 0);
        }
    };

    float acc[4][8];
#pragma unroll
    for (int i = 0; i < 4; ++i)
#pragma unroll
        for (int j = 0; j < 8; ++j) acc[i][j] = 0.f;

    issue(0);
#pragma unroll 1                                   // KEEP ROLLED: I$ working set
    for (int k = 0; k < NCHUNK; ++k) {
        if (k + 1 < NCHUNK) {
            issue(k + 1);                          // next chunk stays in flight
            asm volatile("s_waitcnt vmcnt(6)" ::: "memory");   // chunk k landed
        } else {
            asm volatile("s_waitcnt vmcnt(0)" ::: "memory");
        }
        __builtin_amdgcn_s_barrier();
        __builtin_amdgcn_sched_barrier(0);

        const float4* xc = xb + ((k & 1) << 10);
        const float4* pc = pb + ((k & 1) << 11);
#pragma unroll
        for (int ft = 0; ft < 4; ++ft) {
            const int f = wave * 4 + ft;           // wave's 16-d sub-slice
            float4 xf[4];
#pragma unroll
            for (int i = 0; i < 4; ++i)
                xf[i] = xc[(qg * 4 + i) * 32 + (f ^ qg)];   // 8 distinct bank-quads
#pragma unroll
            for (int j = 0; j < 8; ++j) {
                float4 pf = pc[(cg * 8 + j) * 32 + (f ^ cg)];
#pragma unroll
                for (int i = 0; i < 4; ++i)
                    acc[i][j] += fabsf(xf[i].x - pf.x) + fabsf(xf[i].y - pf.y)
                               + fabsf(xf[i].z - pf.z) + fabsf(xf[i].w - pf.w);
            }
        }
        __builtin_amdgcn_sched_barrier(0);
        __builtin_amdgcn_s_barrier();              // all waves done with this buf
    }

    // --- reduce the 8 wave-partials in LDS, then fused softmax ---
    float* red = lds;                              // [8][32][65] = 66,560 B
#pragma unroll
    for (int i = 0; i < 4; ++i)
#pragma unroll
        for (int j = 0; j < 8; ++j)
            red[(wave * 32 + qg * 4 + i) * 65 + cg * 8 + j] = acc[i][j];
    __syncthreads();

    // wave w owns q rows [w*4, w*4+4); lane = class
#pragma unroll
    for (int r = 0; r < 4; ++r) {
        int q = wave * 4 + r;
        float s = 0.f;
#pragma unroll
        for (int ww = 0; ww < 8; ++ww)
            s += red[(ww * 32 + q) * 65 + lane];
        float nd = -s;
        float m = nd;
#pragma unroll
        for (int off = 32; off; off >>= 1)
            m = fmaxf(m, __shfl_xor(m, off, 64));
        float e = __expf(nd - m);
        float t = e;
#pragma unroll
        for (int off = 32; off; off >>= 1)
            t += __shfl_xor(t, off, 64);
        out[(size_t)(q0 + q) * CN + lane] = e / t;
    }
}

extern "C" void kernel_launch(void* const* d_in, const int* in_sizes, int n_in,
                              void* d_out, int out_size, void* d_ws, size_t ws_size,
                              hipStream_t stream) {
    const float* x = (const float*)d_in[0];   // [8192, 512]
    const float* y = (const float*)d_in[1];   // [64, 5, 512]
    float* out     = (float*)d_out;           // [8192, 64]
    float* proto   = (float*)d_ws;            // [64, 512] scratch

    proto_kernel<<<(CN * DN + 255) / 256, 256, 0, stream>>>(y, proto);
    dist_kernel<<<QN / BQ, THREADS, 0, stream>>>(x, proto, out);
}